// Round 11
// baseline (355.962 us; speedup 1.0000x reference)
//
#include <hip/hip_runtime.h>
#include <cmath>

#define B_  2
#define H_  16
#define S_  4096
#define DK_ 64
#define DM_ 1024

typedef __attribute__((ext_vector_type(8))) short short8;   // 8 bf16 (4 VGPRs)
typedef __attribute__((ext_vector_type(4))) float floatx4;  // MFMA C/D frag

// async global->LDS, 16B per lane; LDS dest wave-uniform base (+lane*16)
#define GLOAD_LDS16(g, l) \
  __builtin_amdgcn_global_load_lds((const __attribute__((address_space(1))) void*)(g), \
                                   (__attribute__((address_space(3))) void*)(l), 16, 0, 0)

__device__ __forceinline__ unsigned short f2bf(float f) {   // RNE fp32 -> bf16
    unsigned u = __builtin_bit_cast(unsigned, f);
    u += 0x7FFFu + ((u >> 16) & 1u);
    return (unsigned short)(u >> 16);
}
// truncating pack: high16(a) -> low half, high16(b) -> high half (1 v_perm)
__device__ __forceinline__ unsigned bfpack_trunc(float a, float b) {
    return __builtin_amdgcn_perm(__builtin_bit_cast(unsigned, b),
                                 __builtin_bit_cast(unsigned, a), 0x07060302u);
}

// ---------------------------------------------------------------------------
// One launch: cast x (8192 blocks) + Wq/Wk/Wv/Wo (1024 blocks each) to bf16.
// dst layout: [x][Wq][Wk][Wv][Wo] contiguous.
// ---------------------------------------------------------------------------
__global__ void cast_all(const float* __restrict__ x,  const float* __restrict__ wq,
                         const float* __restrict__ wk, const float* __restrict__ wv,
                         const float* __restrict__ wo, unsigned short* __restrict__ dst) {
    const int NX = B_ * S_ * DM_, NW = DM_ * DM_;
    int gb = blockIdx.x, lb;
    const float* src;
    size_t dbase;
    if (gb < NX / 1024) { lb = gb; src = x; dbase = 0; }
    else {
        int t = gb - NX / 1024;
        int wi = t >> 10;  lb = t & 1023;
        src = (wi == 0) ? wq : (wi == 1) ? wk : (wi == 2) ? wv : wo;
        dbase = (size_t)NX + (size_t)wi * NW;
    }
    int i = (lb * 256 + threadIdx.x) * 4;
    float4 v = *(const float4*)(src + i);
    uint2 o;
    o.x = (unsigned)f2bf(v.x) | ((unsigned)f2bf(v.y) << 16);
    o.y = (unsigned)f2bf(v.z) | ((unsigned)f2bf(v.w) << 16);
    *(uint2*)(dst + dbase + i) = o;
}

// ---------------------------------------------------------------------------
// Fused Q+K+V projections, ONE launch. Grid (64 s-tiles, 24):
//   y in [0,16): W-orientation C[f][s] = W x X^T, fused RoPE -> (b,h,s,d);
//                y>>3 = 0 -> Q (scale log2e/8), 1 -> K.
//   y in [16,24): X-orientation C[s][f] = X x Wv^T -> V^T (b,h,d,s).
// x = s-tile: all 24 blocks sharing an X s-tile land on one XCD (id%8=x%8).
// Path select is block-uniform; loop structure identical (same barrier count).
// ---------------------------------------------------------------------------
__global__ __launch_bounds__(256) void gemm_qkv(const unsigned short* __restrict__ Wb,
                                                const unsigned short* __restrict__ Xb,
                                                unsigned short* __restrict__ Qb,
                                                unsigned short* __restrict__ Kb,
                                                unsigned short* __restrict__ Vtb,
                                                const int* __restrict__ pos) {
    __shared__ __align__(16) unsigned short Al[128 * 64];
    __shared__ __align__(16) unsigned short Bl[128 * 64];
    const int tid = threadIdx.x, lane = tid & 63, w = tid >> 6;
    const int quad = lane >> 4, l15 = lane & 15;
    const int yb = blockIdx.y;
    const bool vpath = (yb >= 16);
    const unsigned short *Ag, *Bg;
    int bm, bn;
    if (!vpath) {                 // Q/K: A = W (features), B = X (s)
        Ag = Wb + (size_t)(yb >> 3) * (DM_ * DM_);
        Bg = Xb;
        bm = (yb & 7) * 128;  bn = blockIdx.x * 128;
    } else {                      // V: A = X (s), B = Wv (features)
        Ag = Xb;
        Bg = Wb + (size_t)2 * (DM_ * DM_);
        bm = blockIdx.x * 128;  bn = (yb - 16) * 128;
    }
    const int wm = (w & 1) * 64, wn = (w >> 1) * 64;

    floatx4 acc[4][4];
#pragma unroll
    for (int i = 0; i < 4; ++i)
#pragma unroll
        for (int j = 0; j < 4; ++j) acc[i][j] = (floatx4)0.0f;

    for (int k0 = 0; k0 < DM_; k0 += 64) {
        __syncthreads();
#pragma unroll
        for (int i = 0; i < 4; ++i) {
            int chunk = i * 256 + w * 64 + lane;
            int row = chunk >> 3, cc = chunk & 7;
            int gc = cc ^ (row & 7);                   // XOR chunk swizzle
            GLOAD_LDS16(Ag + (size_t)(bm + row) * DM_ + k0 + gc * 8, &Al[(i * 256 + w * 64) * 8]);
            GLOAD_LDS16(Bg + (size_t)(bn + row) * DM_ + k0 + gc * 8, &Bl[(i * 256 + w * 64) * 8]);
        }
        __syncthreads();
#pragma unroll
        for (int s = 0; s < 2; ++s) {
            short8 Af[4], Bf[4];
#pragma unroll
            for (int t = 0; t < 4; ++t) {
                int ra = wm + t * 16 + l15;
                Af[t] = *(const short8*)&Al[ra * 64 + (((s * 4 + quad) ^ (ra & 7)) << 3)];
                int rb = wn + t * 16 + l15;
                Bf[t] = *(const short8*)&Bl[rb * 64 + (((s * 4 + quad) ^ (rb & 7)) << 3)];
            }
#pragma unroll
            for (int i = 0; i < 4; ++i)
#pragma unroll
                for (int j = 0; j < 4; ++j)
                    acc[i][j] = __builtin_amdgcn_mfma_f32_16x16x32_bf16(Af[i], Bf[j], acc[i][j], 0, 0, 0);
        }
    }

    if (!vpath) {   // ---- RoPE epilogue -> bf16 (b,h,s,d), 8B stores ----
        unsigned short* Y = (yb >> 3) ? Kb : Qb;
        const float scale = (yb >> 3) ? 1.0f : 0.125f * 1.44269504f;
        float freqs[4][2];   // 10000^(-j/32) / (2*pi): revolutions per unit pos
#pragma unroll
        for (int i = 0; i < 4; ++i) {
            int d0 = (wm + i * 16 + quad * 4) & 63;
            int j0 = d0 >> 1;
            freqs[i][0] = exp2f((float)j0 * -0.415241011861f) * 0.15915494309f;
            freqs[i][1] = exp2f((float)(j0 + 1) * -0.415241011861f) * 0.15915494309f;
        }
#pragma unroll
        for (int j = 0; j < 4; ++j) {
            int sg = bn + wn + j * 16 + l15;
            int b = sg >> 12, s = sg & (S_ - 1);
            float pp = (float)pos[sg];
#pragma unroll
            for (int i = 0; i < 4; ++i) {
                int f0 = bm + wm + i * 16 + quad * 4;
                int h = f0 >> 6, d0 = f0 & 63;
                unsigned short pk[4];
#pragma unroll
                for (int pr = 0; pr < 2; ++pr) {
                    float rev = pp * freqs[i][pr];
                    rev -= rintf(rev);                       // |rev| <= 0.5
                    float ang = rev * 6.28318530718f;        // |ang| <= pi
                    float sn = __sinf(ang), cs = __cosf(ang);
                    float e = acc[i][j][2 * pr], od = acc[i][j][2 * pr + 1];
                    pk[2 * pr]     = f2bf((e * cs - od * sn) * scale);
                    pk[2 * pr + 1] = f2bf((e * sn + od * cs) * scale);
                }
                *(uint2*)&Y[((size_t)(b * H_ + h) * S_ + s) * DK_ + d0] = *(uint2*)pk;
            }
        }
    } else {        // ---- V^T epilogue -> (b,h,d,s), 8B packed stores ----
#pragma unroll
        for (int i = 0; i < 4; ++i) {
            int m0 = bm + wm + i * 16 + quad * 4;
            int b = m0 >> 12, s0 = m0 & (S_ - 1);
#pragma unroll
            for (int j = 0; j < 4; ++j) {
                int n = bn + wn + j * 16 + l15;
                int h = n >> 6, d = n & 63;
                unsigned short pk[4];
#pragma unroll
                for (int r = 0; r < 4; ++r) pk[r] = f2bf(acc[i][j][r]);
                *(uint2*)&Vtb[((size_t)(b * H_ + h) * DK_ + d) * S_ + s0] = *(uint2*)pk;
            }
        }
    }
}

// ---------------------------------------------------------------------------
// O-projection GEMM, W-orientation, fp32 out[s][f] with float4 stores.
// ---------------------------------------------------------------------------
__global__ __launch_bounds__(256) void gemm_out(const unsigned short* __restrict__ Ag,
                                                const unsigned short* __restrict__ Bg,
                                                float* __restrict__ Y) {
    __shared__ __align__(16) unsigned short Al[128 * 64];
    __shared__ __align__(16) unsigned short Bl[128 * 64];
    const int tid = threadIdx.x, lane = tid & 63, w = tid >> 6;
    const int quad = lane >> 4, l15 = lane & 15;
    const int bm = blockIdx.y * 128, bn = blockIdx.x * 128;   // m=feature, n=s
    const int wm = (w & 1) * 64, wn = (w >> 1) * 64;

    floatx4 acc[4][4];
#pragma unroll
    for (int i = 0; i < 4; ++i)
#pragma unroll
        for (int j = 0; j < 4; ++j) acc[i][j] = (floatx4)0.0f;

    for (int k0 = 0; k0 < DM_; k0 += 64) {
        __syncthreads();
#pragma unroll
        for (int i = 0; i < 4; ++i) {
            int chunk = i * 256 + w * 64 + lane;
            int row = chunk >> 3, cc = chunk & 7;
            int gc = cc ^ (row & 7);
            GLOAD_LDS16(Ag + (size_t)(bm + row) * DM_ + k0 + gc * 8, &Al[(i * 256 + w * 64) * 8]);
            GLOAD_LDS16(Bg + (size_t)(bn + row) * DM_ + k0 + gc * 8, &Bl[(i * 256 + w * 64) * 8]);
        }
        __syncthreads();
#pragma unroll
        for (int s = 0; s < 2; ++s) {
            short8 Af[4], Bf[4];
#pragma unroll
            for (int t = 0; t < 4; ++t) {
                int ra = wm + t * 16 + l15;
                Af[t] = *(const short8*)&Al[ra * 64 + (((s * 4 + quad) ^ (ra & 7)) << 3)];
                int rb = wn + t * 16 + l15;
                Bf[t] = *(const short8*)&Bl[rb * 64 + (((s * 4 + quad) ^ (rb & 7)) << 3)];
            }
#pragma unroll
            for (int i = 0; i < 4; ++i)
#pragma unroll
                for (int j = 0; j < 4; ++j)
                    acc[i][j] = __builtin_amdgcn_mfma_f32_16x16x32_bf16(Af[i], Bf[j], acc[i][j], 0, 0, 0);
        }
    }

#pragma unroll
    for (int i = 0; i < 4; ++i) {
        int f0 = bm + wm + i * 16 + quad * 4;
#pragma unroll
        for (int j = 0; j < 4; ++j) {
            int sg = bn + wn + j * 16 + l15;
            float4 v = make_float4(acc[i][j][0], acc[i][j][1], acc[i][j][2], acc[i][j][3]);
            *(float4*)&Y[(size_t)sg * DM_ + f0] = v;
        }
    }
}

// ---------------------------------------------------------------------------
// MFMA flash attention v9. Grid (32 bh, 32 qt), qt = 31 - y (heavy first),
// XCD-pinned by bh. P shrunk to an 8 KB half-buffer: PV consumes P in 32-key
// halves, LDS ops are FIFO per wave, so each ks-half writes then reads the
// SAME buffer (wave-private rows, no barrier). LDS 40 KB -> 4 blocks/CU
// (16 waves) with launch_bounds(256,4) (VGPR cap 128, kernel uses ~80).
// The per-ks split also interleaves exp (VALU) with PV (MFMA) inside a wave.
// No-shift base-2 softmax (Q carries log2e/8); l via ones-MFMA (truncation
// bias cancels in O = PV/l); all LDS offsets hoisted to VGPRs.
// ---------------------------------------------------------------------------
__global__ __launch_bounds__(256, 4) void attn_mfma(const unsigned short* __restrict__ Qg,
                                                    const unsigned short* __restrict__ Kg,
                                                    const unsigned short* __restrict__ Vtg,
                                                    unsigned short* __restrict__ Og) {
    __shared__ __align__(16) unsigned short Kl[2][64 * 64];   // [key][swizzled d]   16 KB
    __shared__ __align__(16) unsigned short Vl[2][64 * 64];   // [d][swizzled key]   16 KB
    __shared__ __align__(16) unsigned short Pl[128 * 32];     // [q][swizzled key32]  8 KB

    const int bh = blockIdx.x;
    const int qt = 31 - blockIdx.y;          // heavy tiles dispatch first
    const int tid = threadIdx.x, lane = tid & 63, w = tid >> 6;
    const int quad = lane >> 4, l15 = lane & 15;
    const int b = bh >> 4, h = bh & 15;
    const int qbase = qt * 128 + w * 32;

    const short one_bf = (short)0x3F80;   // bf16 1.0
    const short8 ones8 = {one_bf, one_bf, one_bf, one_bf, one_bf, one_bf, one_bf, one_bf};
    const floatx4 fzero = (floatx4)0.0f;

    const unsigned short* KgB = Kg  + (size_t)bh * S_ * DK_;
    const unsigned short* VgB = Vtg + (size_t)bh * DK_ * S_;

    // ---- hoisted loop-invariant LDS element offsets (live in VGPRs) ----
    int rdoff[2][4];          // K-frag AND V-frag reads (same formula)
#pragma unroll
    for (int ks = 0; ks < 2; ++ks)
#pragma unroll
        for (int t = 0; t < 4; ++t) {
            int row = t * 16 + l15;
            rdoff[ks][t] = row * 64 + (((ks * 4 + quad) ^ (row & 7)) << 3);
        }
    // P half-buffer: row stride 32 shorts (4 chunks of 8 keys), XOR by l15&3.
    int pwoff[2][2], proff[2];
#pragma unroll
    for (int qf = 0; qf < 2; ++qf) {
        int prow = (w * 32 + qf * 16 + l15) * 32;
#pragma unroll
        for (int kf2 = 0; kf2 < 2; ++kf2)   // kf2 = kf within the ks-half
            pwoff[kf2][qf] = prow + (((kf2 * 2 + (quad >> 1)) ^ (l15 & 3)) << 3) + (quad & 1) * 4;
        proff[qf] = prow + ((quad ^ (l15 & 3)) << 3);
    }
    int qv[2] = {qbase + l15, qbase + 16 + l15};   // causal mask compare

    // Q B-frags: n = qbase + qf*16 + l15, k = ks*32 + quad*8 + j
    const unsigned short* Qbase = Qg + ((size_t)bh * S_ + qbase + l15) * DK_;
    short8 Qf[2][2];
#pragma unroll
    for (int qf = 0; qf < 2; ++qf)
#pragma unroll
        for (int ks = 0; ks < 2; ++ks)
            Qf[qf][ks] = *(const short8*)(Qbase + qf * 16 * DK_ + ks * 32 + quad * 8);

    floatx4 o[4][2];      // [df][qf], O^T accum
    floatx4 lacc[2];      // per-qf row-sum accum (all C rows equal)
#pragma unroll
    for (int df = 0; df < 4; ++df)
#pragma unroll
        for (int qf = 0; qf < 2; ++qf) o[df][qf] = (floatx4)0.0f;
#pragma unroll
    for (int qf = 0; qf < 2; ++qf) lacc[qf] = (floatx4)0.0f;

#define STAGE(bsel, ktt)                                                        \
    {                                                                           \
        _Pragma("unroll")                                                       \
        for (int i = 0; i < 2; ++i) {                                           \
            int chunk = i * 256 + w * 64 + lane;                                \
            int row = chunk >> 3, cc = chunk & 7;                               \
            int gc = cc ^ (row & 7);                                            \
            GLOAD_LDS16(KgB + (size_t)((ktt) * 64 + row) * DK_ + gc * 8,        \
                        &Kl[bsel][(i * 256 + w * 64) * 8]);                     \
            GLOAD_LDS16(VgB + (size_t)row * S_ + (ktt) * 64 + gc * 8,           \
                        &Vl[bsel][(i * 256 + w * 64) * 8]);                     \
        }                                                                       \
    }

#define COMPUTE(bufc, ktc)                                                      \
    {                                                                           \
        floatx4 sc[4][2];                                                       \
        {   /* QK ks=0: init via zero-C MFMA */                                 \
            short8 Kf[4];                                                       \
            _Pragma("unroll")                                                   \
            for (int kf = 0; kf < 4; ++kf)                                      \
                Kf[kf] = *(const short8*)&Kl[bufc][rdoff[0][kf]];               \
            _Pragma("unroll")                                                   \
            for (int kf = 0; kf < 4; ++kf)                                      \
                _Pragma("unroll")                                               \
                for (int qf = 0; qf < 2; ++qf)                                  \
                    sc[kf][qf] = __builtin_amdgcn_mfma_f32_16x16x32_bf16(Kf[kf], Qf[qf][0], fzero, 0, 0, 0); \
        }                                                                       \
        {   /* QK ks=1: accumulate */                                           \
            short8 Kf[4];                                                       \
            _Pragma("unroll")                                                   \
            for (int kf = 0; kf < 4; ++kf)                                      \
                Kf[kf] = *(const short8*)&Kl[bufc][rdoff[1][kf]];               \
            _Pragma("unroll")                                                   \
            for (int kf = 0; kf < 4; ++kf)                                      \
                _Pragma("unroll")                                               \
                for (int qf = 0; qf < 2; ++qf)                                  \
                    sc[kf][qf] = __builtin_amdgcn_mfma_f32_16x16x32_bf16(Kf[kf], Qf[qf][1], sc[kf][qf], 0, 0, 0); \
        }                                                                       \
        if ((ktc) * 64 + 63 > qbase) {  /* tile straddles diagonal */           \
            _Pragma("unroll")                                                   \
            for (int kf = 0; kf < 4; ++kf)                                      \
                _Pragma("unroll")                                               \
                for (int qf = 0; qf < 2; ++qf)                                  \
                    _Pragma("unroll")                                           \
                    for (int r = 0; r < 4; ++r) {                               \
                        int key = (ktc) * 64 + kf * 16 + quad * 4 + r;          \
                        if (key > qv[qf]) sc[kf][qf][r] = -1e30f;               \
                    }                                                           \
        }                                                                       \
        _Pragma("unroll")                                                       \
        for (int ks = 0; ks < 2; ++ks) {   /* per 32-key half: exp -> P -> PV */\
            _Pragma("unroll")                                                   \
            for (int kf2 = 0; kf2 < 2; ++kf2) {                                 \
                int kf = ks * 2 + kf2;                                          \
                _Pragma("unroll")                                               \
                for (int qf = 0; qf < 2; ++qf) {                                \
                    float p0 = __builtin_exp2f(sc[kf][qf][0]);                  \
                    float p1 = __builtin_exp2f(sc[kf][qf][1]);                  \
                    float p2 = __builtin_exp2f(sc[kf][qf][2]);                  \
                    float p3 = __builtin_exp2f(sc[kf][qf][3]);                  \
                    uint2 pk;                                                   \
                    pk.x = bfpack_trunc(p0, p1);                                \
                    pk.y = bfpack_trunc(p2, p3);                                \
                    *(uint2*)&Pl[pwoff[kf2][qf]] = pk;                          \
                }                                                               \
            }                                                                   \
            short8 Vf[4], Pf[2];                                                \
            _Pragma("unroll")                                                   \
            for (int df = 0; df < 4; ++df)                                      \
                Vf[df] = *(const short8*)&Vl[bufc][rdoff[ks][df]];              \
            _Pragma("unroll")                                                   \
            for (int qf = 0; qf < 2; ++qf)                                      \
                Pf[qf] = *(const short8*)&Pl[proff[qf]];                        \
            _Pragma("unroll")                                                   \
            for (int df = 0; df < 4; ++df)                                      \
                _Pragma("unroll")                                               \
                for (int qf = 0; qf < 2; ++qf)                                  \
                    o[df][qf] = __builtin_amdgcn_mfma_f32_16x16x32_bf16(Vf[df], Pf[qf], o[df][qf], 0, 0, 0); \
            _Pragma("unroll")                                                   \
            for (int qf = 0; qf < 2; ++qf)                                      \
                lacc[qf] = __builtin_amdgcn_mfma_f32_16x16x32_bf16(ones8, Pf[qf], lacc[qf], 0, 0, 0); \
        }                                                                       \
    }

    const int ktmax = 2 * qt + 1;            // iteration count 2qt+2: even
    STAGE(0, 0);
    for (int kt = 0; kt <= ktmax; kt += 2) {
        __syncthreads();                     // staging(kt) visible
        if (kt < ktmax) STAGE(1, kt + 1);
        if (qbase + 31 >= kt * 64) COMPUTE(0, kt);

        __syncthreads();                     // staging(kt+1) visible
        if (kt + 1 < ktmax) STAGE(0, kt + 2);
        if (qbase + 31 >= (kt + 1) * 64) COMPUTE(1, kt + 1);
    }

    // ---- epilogue: l is in-lane (all C rows equal) -> no shuffles ----
    float inv[2];
#pragma unroll
    for (int qf = 0; qf < 2; ++qf) inv[qf] = 1.0f / lacc[qf][0];
#pragma unroll
    for (int df = 0; df < 4; ++df)
#pragma unroll
        for (int qf = 0; qf < 2; ++qf) {
            int q  = qbase + qf * 16 + l15;
            int dd = df * 16 + quad * 4;
            unsigned short pk[4];
#pragma unroll
            for (int r = 0; r < 4; ++r) pk[r] = f2bf(o[df][qf][r] * inv[qf]);
            *(uint2*)&Og[((size_t)b * S_ + q) * DM_ + h * DK_ + dd] = *(uint2*)pk;
        }
#undef COMPUTE
#undef STAGE
}

// ---------------------------------------------------------------------------
extern "C" void kernel_launch(void* const* d_in, const int* in_sizes, int n_in,
                              void* d_out, int out_size, void* d_ws, size_t ws_size,
                              hipStream_t stream) {
    const float* x    = (const float*)d_in[0];
    const int*   tpos = (const int*)d_in[1];
    const float* Wq   = (const float*)d_in[2];
    const float* Wk   = (const float*)d_in[3];
    const float* Wv   = (const float*)d_in[4];
    const float* Wo   = (const float*)d_in[5];
    float* out = (float*)d_out;

    const int NX = B_ * S_ * DM_;        // 8388608
    const int NW = DM_ * DM_;            // 1048576

    unsigned short* xb  = (unsigned short*)d_ws;
    unsigned short* Wqb = xb + NX;       // Wq,Wk,Wv,Wo contiguous
    unsigned short* Wob = Wqb + 3 * NW;
    unsigned short* Qb  = Wob + NW;
    unsigned short* Kb  = Qb + NX;
    unsigned short* Vtb = Kb + NX;
    unsigned short* Aw  = Vtb + NX;

    cast_all<<<NX / 1024 + 4 * (NW / 1024), 256, 0, stream>>>(x, Wq, Wk, Wv, Wo, xb);

    gemm_qkv<<<dim3(64, 24), 256, 0, stream>>>(Wqb, xb, Qb, Kb, Vtb, tpos);

    attn_mfma<<<dim3(32, 32), 256, 0, stream>>>(Qb, Kb, Vtb, Aw);

    gemm_out<<<dim3(64, 8), 256, 0, stream>>>(Wob, Aw, out);            // O-proj, fp32 out
}

// Round 12
// 294.529 us; speedup vs baseline: 1.2086x; 1.2086x over previous
//
#include <hip/hip_runtime.h>
#include <cmath>

#define B_  2
#define H_  16
#define S_  4096
#define DK_ 64
#define DM_ 1024

typedef __attribute__((ext_vector_type(8))) short short8;   // 8 bf16 (4 VGPRs)
typedef __attribute__((ext_vector_type(4))) float floatx4;  // MFMA C/D frag

// async global->LDS, 16B per lane; LDS dest wave-uniform base (+lane*16)
#define GLOAD_LDS16(g, l) \
  __builtin_amdgcn_global_load_lds((const __attribute__((address_space(1))) void*)(g), \
                                   (__attribute__((address_space(3))) void*)(l), 16, 0, 0)

__device__ __forceinline__ unsigned short f2bf(float f) {   // RNE fp32 -> bf16
    unsigned u = __builtin_bit_cast(unsigned, f);
    u += 0x7FFFu + ((u >> 16) & 1u);
    return (unsigned short)(u >> 16);
}
// truncating pack: high16(a) -> low half, high16(b) -> high half (1 v_perm)
__device__ __forceinline__ unsigned bfpack_trunc(float a, float b) {
    return __builtin_amdgcn_perm(__builtin_bit_cast(unsigned, b),
                                 __builtin_bit_cast(unsigned, a), 0x07060302u);
}

// ---------------------------------------------------------------------------
// One launch: cast x (8192 blocks) + Wq/Wk/Wv/Wo (1024 blocks each) to bf16.
// dst layout: [x][Wq][Wk][Wv][Wo] contiguous.
// ---------------------------------------------------------------------------
__global__ void cast_all(const float* __restrict__ x,  const float* __restrict__ wq,
                         const float* __restrict__ wk, const float* __restrict__ wv,
                         const float* __restrict__ wo, unsigned short* __restrict__ dst) {
    const int NX = B_ * S_ * DM_, NW = DM_ * DM_;
    int gb = blockIdx.x, lb;
    const float* src;
    size_t dbase;
    if (gb < NX / 1024) { lb = gb; src = x; dbase = 0; }
    else {
        int t = gb - NX / 1024;
        int wi = t >> 10;  lb = t & 1023;
        src = (wi == 0) ? wq : (wi == 1) ? wk : (wi == 2) ? wv : wo;
        dbase = (size_t)NX + (size_t)wi * NW;
    }
    int i = (lb * 256 + threadIdx.x) * 4;
    float4 v = *(const float4*)(src + i);
    uint2 o;
    o.x = (unsigned)f2bf(v.x) | ((unsigned)f2bf(v.y) << 16);
    o.y = (unsigned)f2bf(v.z) | ((unsigned)f2bf(v.w) << 16);
    *(uint2*)(dst + dbase + i) = o;
}

// ---------------------------------------------------------------------------
// Fused Q+K+V projections, ONE launch. Grid (64 s-tiles, 24):
//   y in [0,16): W-orientation C[f][s] = W x X^T, fused RoPE -> (b,h,s,d);
//                y>>3 = 0 -> Q (scale log2e/8), 1 -> K.
//   y in [16,24): X-orientation C[s][f] = X x Wv^T -> V^T (b,h,d,s).
// x = s-tile: all 24 blocks sharing an X s-tile land on one XCD (id%8=x%8).
// ---------------------------------------------------------------------------
__global__ __launch_bounds__(256) void gemm_qkv(const unsigned short* __restrict__ Wb,
                                                const unsigned short* __restrict__ Xb,
                                                unsigned short* __restrict__ Qb,
                                                unsigned short* __restrict__ Kb,
                                                unsigned short* __restrict__ Vtb,
                                                const int* __restrict__ pos) {
    __shared__ __align__(16) unsigned short Al[128 * 64];
    __shared__ __align__(16) unsigned short Bl[128 * 64];
    const int tid = threadIdx.x, lane = tid & 63, w = tid >> 6;
    const int quad = lane >> 4, l15 = lane & 15;
    const int yb = blockIdx.y;
    const bool vpath = (yb >= 16);
    const unsigned short *Ag, *Bg;
    int bm, bn;
    if (!vpath) {                 // Q/K: A = W (features), B = X (s)
        Ag = Wb + (size_t)(yb >> 3) * (DM_ * DM_);
        Bg = Xb;
        bm = (yb & 7) * 128;  bn = blockIdx.x * 128;
    } else {                      // V: A = X (s), B = Wv (features)
        Ag = Xb;
        Bg = Wb + (size_t)2 * (DM_ * DM_);
        bm = blockIdx.x * 128;  bn = (yb - 16) * 128;
    }
    const int wm = (w & 1) * 64, wn = (w >> 1) * 64;

    floatx4 acc[4][4];
#pragma unroll
    for (int i = 0; i < 4; ++i)
#pragma unroll
        for (int j = 0; j < 4; ++j) acc[i][j] = (floatx4)0.0f;

    for (int k0 = 0; k0 < DM_; k0 += 64) {
        __syncthreads();
#pragma unroll
        for (int i = 0; i < 4; ++i) {
            int chunk = i * 256 + w * 64 + lane;
            int row = chunk >> 3, cc = chunk & 7;
            int gc = cc ^ (row & 7);                   // XOR chunk swizzle
            GLOAD_LDS16(Ag + (size_t)(bm + row) * DM_ + k0 + gc * 8, &Al[(i * 256 + w * 64) * 8]);
            GLOAD_LDS16(Bg + (size_t)(bn + row) * DM_ + k0 + gc * 8, &Bl[(i * 256 + w * 64) * 8]);
        }
        __syncthreads();
#pragma unroll
        for (int s = 0; s < 2; ++s) {
            short8 Af[4], Bf[4];
#pragma unroll
            for (int t = 0; t < 4; ++t) {
                int ra = wm + t * 16 + l15;
                Af[t] = *(const short8*)&Al[ra * 64 + (((s * 4 + quad) ^ (ra & 7)) << 3)];
                int rb = wn + t * 16 + l15;
                Bf[t] = *(const short8*)&Bl[rb * 64 + (((s * 4 + quad) ^ (rb & 7)) << 3)];
            }
#pragma unroll
            for (int i = 0; i < 4; ++i)
#pragma unroll
                for (int j = 0; j < 4; ++j)
                    acc[i][j] = __builtin_amdgcn_mfma_f32_16x16x32_bf16(Af[i], Bf[j], acc[i][j], 0, 0, 0);
        }
    }

    if (!vpath) {   // ---- RoPE epilogue -> bf16 (b,h,s,d), 8B stores ----
        unsigned short* Y = (yb >> 3) ? Kb : Qb;
        const float scale = (yb >> 3) ? 1.0f : 0.125f * 1.44269504f;
        float freqs[4][2];   // 10000^(-j/32) / (2*pi): revolutions per unit pos
#pragma unroll
        for (int i = 0; i < 4; ++i) {
            int d0 = (wm + i * 16 + quad * 4) & 63;
            int j0 = d0 >> 1;
            freqs[i][0] = exp2f((float)j0 * -0.415241011861f) * 0.15915494309f;
            freqs[i][1] = exp2f((float)(j0 + 1) * -0.415241011861f) * 0.15915494309f;
        }
#pragma unroll
        for (int j = 0; j < 4; ++j) {
            int sg = bn + wn + j * 16 + l15;
            int b = sg >> 12, s = sg & (S_ - 1);
            float pp = (float)pos[sg];
#pragma unroll
            for (int i = 0; i < 4; ++i) {
                int f0 = bm + wm + i * 16 + quad * 4;
                int h = f0 >> 6, d0 = f0 & 63;
                unsigned short pk[4];
#pragma unroll
                for (int pr = 0; pr < 2; ++pr) {
                    float rev = pp * freqs[i][pr];
                    rev -= rintf(rev);                       // |rev| <= 0.5
                    float ang = rev * 6.28318530718f;        // |ang| <= pi
                    float sn = __sinf(ang), cs = __cosf(ang);
                    float e = acc[i][j][2 * pr], od = acc[i][j][2 * pr + 1];
                    pk[2 * pr]     = f2bf((e * cs - od * sn) * scale);
                    pk[2 * pr + 1] = f2bf((e * sn + od * cs) * scale);
                }
                *(uint2*)&Y[((size_t)(b * H_ + h) * S_ + s) * DK_ + d0] = *(uint2*)pk;
            }
        }
    } else {        // ---- V^T epilogue -> (b,h,d,s), 8B packed stores ----
#pragma unroll
        for (int i = 0; i < 4; ++i) {
            int m0 = bm + wm + i * 16 + quad * 4;
            int b = m0 >> 12, s0 = m0 & (S_ - 1);
#pragma unroll
            for (int j = 0; j < 4; ++j) {
                int n = bn + wn + j * 16 + l15;
                int h = n >> 6, d = n & 63;
                unsigned short pk[4];
#pragma unroll
                for (int r = 0; r < 4; ++r) pk[r] = f2bf(acc[i][j][r]);
                *(uint2*)&Vtb[((size_t)(b * H_ + h) * DK_ + d) * S_ + s0] = *(uint2*)pk;
            }
        }
    }
}

// ---------------------------------------------------------------------------
// O-projection GEMM, W-orientation, fp32 out[s][f] with float4 stores.
// ---------------------------------------------------------------------------
__global__ __launch_bounds__(256) void gemm_out(const unsigned short* __restrict__ Ag,
                                                const unsigned short* __restrict__ Bg,
                                                float* __restrict__ Y) {
    __shared__ __align__(16) unsigned short Al[128 * 64];
    __shared__ __align__(16) unsigned short Bl[128 * 64];
    const int tid = threadIdx.x, lane = tid & 63, w = tid >> 6;
    const int quad = lane >> 4, l15 = lane & 15;
    const int bm = blockIdx.y * 128, bn = blockIdx.x * 128;   // m=feature, n=s
    const int wm = (w & 1) * 64, wn = (w >> 1) * 64;

    floatx4 acc[4][4];
#pragma unroll
    for (int i = 0; i < 4; ++i)
#pragma unroll
        for (int j = 0; j < 4; ++j) acc[i][j] = (floatx4)0.0f;

    for (int k0 = 0; k0 < DM_; k0 += 64) {
        __syncthreads();
#pragma unroll
        for (int i = 0; i < 4; ++i) {
            int chunk = i * 256 + w * 64 + lane;
            int row = chunk >> 3, cc = chunk & 7;
            int gc = cc ^ (row & 7);
            GLOAD_LDS16(Ag + (size_t)(bm + row) * DM_ + k0 + gc * 8, &Al[(i * 256 + w * 64) * 8]);
            GLOAD_LDS16(Bg + (size_t)(bn + row) * DM_ + k0 + gc * 8, &Bl[(i * 256 + w * 64) * 8]);
        }
        __syncthreads();
#pragma unroll
        for (int s = 0; s < 2; ++s) {
            short8 Af[4], Bf[4];
#pragma unroll
            for (int t = 0; t < 4; ++t) {
                int ra = wm + t * 16 + l15;
                Af[t] = *(const short8*)&Al[ra * 64 + (((s * 4 + quad) ^ (ra & 7)) << 3)];
                int rb = wn + t * 16 + l15;
                Bf[t] = *(const short8*)&Bl[rb * 64 + (((s * 4 + quad) ^ (rb & 7)) << 3)];
            }
#pragma unroll
            for (int i = 0; i < 4; ++i)
#pragma unroll
                for (int j = 0; j < 4; ++j)
                    acc[i][j] = __builtin_amdgcn_mfma_f32_16x16x32_bf16(Af[i], Bf[j], acc[i][j], 0, 0, 0);
        }
    }

#pragma unroll
    for (int i = 0; i < 4; ++i) {
        int f0 = bm + wm + i * 16 + quad * 4;
#pragma unroll
        for (int j = 0; j < 4; ++j) {
            int sg = bn + wn + j * 16 + l15;
            float4 v = make_float4(acc[i][j][0], acc[i][j][1], acc[i][j][2], acc[i][j][3]);
            *(float4*)&Y[(size_t)sg * DM_ + f0] = v;
        }
    }
}

// ---------------------------------------------------------------------------
// MFMA flash attention v8 (R9 configuration — the 121 us point; R10's
// half-buffer + (256,4) variant spilled to scratch and conflicted, reverted).
// Grid (32 bh, 32 qt), qt = 31 - y (heavy first), XCD-pinned by bh.
// 48 KB LDS -> 3 resident blocks/CU; launch_bounds(256,3) (VGPR cap ~168,
// kernel uses ~76 - no spills). All loop-invariant LDS offsets hoisted.
// No-shift base-2 softmax (Q carries log2e/8): p = exp2(s); l via ones-MFMA
// (truncation bias cancels in O = PV/l); pad-free XOR-swizzled 64-stride P.
// ---------------------------------------------------------------------------
__global__ __launch_bounds__(256, 3) void attn_mfma(const unsigned short* __restrict__ Qg,
                                                    const unsigned short* __restrict__ Kg,
                                                    const unsigned short* __restrict__ Vtg,
                                                    unsigned short* __restrict__ Og) {
    __shared__ __align__(16) unsigned short Kl[2][64 * 64];   // [key][swizzled d]   16 KB
    __shared__ __align__(16) unsigned short Vl[2][64 * 64];   // [d][swizzled key]   16 KB
    __shared__ __align__(16) unsigned short Pl[128 * 64];     // [q][swizzled key]   16 KB

    const int bh = blockIdx.x;
    const int qt = 31 - blockIdx.y;          // heavy tiles dispatch first
    const int tid = threadIdx.x, lane = tid & 63, w = tid >> 6;
    const int quad = lane >> 4, l15 = lane & 15;
    const int b = bh >> 4, h = bh & 15;
    const int qbase = qt * 128 + w * 32;

    const short one_bf = (short)0x3F80;   // bf16 1.0
    const short8 ones8 = {one_bf, one_bf, one_bf, one_bf, one_bf, one_bf, one_bf, one_bf};
    const floatx4 fzero = (floatx4)0.0f;

    const unsigned short* KgB = Kg  + (size_t)bh * S_ * DK_;
    const unsigned short* VgB = Vtg + (size_t)bh * DK_ * S_;

    // ---- hoisted loop-invariant LDS element offsets (live in VGPRs) ----
    int rdoff[2][4];          // K-frag AND V-frag reads (same formula)
#pragma unroll
    for (int ks = 0; ks < 2; ++ks)
#pragma unroll
        for (int t = 0; t < 4; ++t) {
            int row = t * 16 + l15;
            rdoff[ks][t] = row * 64 + (((ks * 4 + quad) ^ (row & 7)) << 3);
        }
    int pwoff[4][2], proff[2][2];
#pragma unroll
    for (int qf = 0; qf < 2; ++qf) {
        int prow = (w * 32 + qf * 16 + l15) * 64;
#pragma unroll
        for (int kf = 0; kf < 4; ++kf)
            pwoff[kf][qf] = prow + ((((2 * kf + (quad >> 1)) ^ (l15 & 7)) << 3) + (quad & 1) * 4);
#pragma unroll
        for (int ks = 0; ks < 2; ++ks)
            proff[ks][qf] = prow + (((ks * 4 + quad) ^ (l15 & 7)) << 3);
    }
    int qv[2] = {qbase + l15, qbase + 16 + l15};   // for causal mask compare

    // Q B-frags: n = qbase + qf*16 + l15, k = ks*32 + quad*8 + j
    const unsigned short* Qbase = Qg + ((size_t)bh * S_ + qbase + l15) * DK_;
    short8 Qf[2][2];
#pragma unroll
    for (int qf = 0; qf < 2; ++qf)
#pragma unroll
        for (int ks = 0; ks < 2; ++ks)
            Qf[qf][ks] = *(const short8*)(Qbase + qf * 16 * DK_ + ks * 32 + quad * 8);

    floatx4 o[4][2];      // [df][qf], O^T accum
    floatx4 lacc[2];      // per-qf row-sum accum (all C rows equal)
#pragma unroll
    for (int df = 0; df < 4; ++df)
#pragma unroll
        for (int qf = 0; qf < 2; ++qf) o[df][qf] = (floatx4)0.0f;
#pragma unroll
    for (int qf = 0; qf < 2; ++qf) lacc[qf] = (floatx4)0.0f;

#define STAGE(bsel, ktt)                                                        \
    {                                                                           \
        _Pragma("unroll")                                                       \
        for (int i = 0; i < 2; ++i) {                                           \
            int chunk = i * 256 + w * 64 + lane;                                \
            int row = chunk >> 3, cc = chunk & 7;                               \
            int gc = cc ^ (row & 7);                                            \
            GLOAD_LDS16(KgB + (size_t)((ktt) * 64 + row) * DK_ + gc * 8,        \
                        &Kl[bsel][(i * 256 + w * 64) * 8]);                     \
            GLOAD_LDS16(VgB + (size_t)row * S_ + (ktt) * 64 + gc * 8,           \
                        &Vl[bsel][(i * 256 + w * 64) * 8]);                     \
        }                                                                       \
    }

#define COMPUTE(bufc, ktc)                                                      \
    {                                                                           \
        floatx4 sc[4][2];                                                       \
        {   /* ks = 0: init via zero-C MFMA */                                  \
            short8 Kf[4];                                                       \
            _Pragma("unroll")                                                   \
            for (int kf = 0; kf < 4; ++kf)                                      \
                Kf[kf] = *(const short8*)&Kl[bufc][rdoff[0][kf]];               \
            _Pragma("unroll")                                                   \
            for (int kf = 0; kf < 4; ++kf)                                      \
                _Pragma("unroll")                                               \
                for (int qf = 0; qf < 2; ++qf)                                  \
                    sc[kf][qf] = __builtin_amdgcn_mfma_f32_16x16x32_bf16(Kf[kf], Qf[qf][0], fzero, 0, 0, 0); \
        }                                                                       \
        {   /* ks = 1: accumulate */                                            \
            short8 Kf[4];                                                       \
            _Pragma("unroll")                                                   \
            for (int kf = 0; kf < 4; ++kf)                                      \
                Kf[kf] = *(const short8*)&Kl[bufc][rdoff[1][kf]];               \
            _Pragma("unroll")                                                   \
            for (int kf = 0; kf < 4; ++kf)                                      \
                _Pragma("unroll")                                               \
                for (int qf = 0; qf < 2; ++qf)                                  \
                    sc[kf][qf] = __builtin_amdgcn_mfma_f32_16x16x32_bf16(Kf[kf], Qf[qf][1], sc[kf][qf], 0, 0, 0); \
        }                                                                       \
        if ((ktc) * 64 + 63 > qbase) {  /* tile straddles diagonal */           \
            _Pragma("unroll")                                                   \
            for (int kf = 0; kf < 4; ++kf)                                      \
                _Pragma("unroll")                                               \
                for (int qf = 0; qf < 2; ++qf)                                  \
                    _Pragma("unroll")                                           \
                    for (int r = 0; r < 4; ++r) {                               \
                        int key = (ktc) * 64 + kf * 16 + quad * 4 + r;          \
                        if (key > qv[qf]) sc[kf][qf][r] = -1e30f;               \
                    }                                                           \
        }                                                                       \
        _Pragma("unroll")                                                       \
        for (int kf = 0; kf < 4; ++kf)                                          \
            _Pragma("unroll")                                                   \
            for (int qf = 0; qf < 2; ++qf) {                                    \
                float p0 = __builtin_exp2f(sc[kf][qf][0]);                      \
                float p1 = __builtin_exp2f(sc[kf][qf][1]);                      \
                float p2 = __builtin_exp2f(sc[kf][qf][2]);                      \
                float p3 = __builtin_exp2f(sc[kf][qf][3]);                      \
                uint2 pk;                                                       \
                pk.x = bfpack_trunc(p0, p1);                                    \
                pk.y = bfpack_trunc(p2, p3);                                    \
                *(uint2*)&Pl[pwoff[kf][qf]] = pk;                               \
            }                                                                   \
        _Pragma("unroll")                                                       \
        for (int ks = 0; ks < 2; ++ks) {                                        \
            short8 Vf[4], Pf[2];                                                \
            _Pragma("unroll")                                                   \
            for (int df = 0; df < 4; ++df)                                      \
                Vf[df] = *(const short8*)&Vl[bufc][rdoff[ks][df]];              \
            _Pragma("unroll")                                                   \
            for (int qf = 0; qf < 2; ++qf)                                      \
                Pf[qf] = *(const short8*)&Pl[proff[ks][qf]];                    \
            _Pragma("unroll")                                                   \
            for (int df = 0; df < 4; ++df)                                      \
                _Pragma("unroll")                                               \
                for (int qf = 0; qf < 2; ++qf)                                  \
                    o[df][qf] = __builtin_amdgcn_mfma_f32_16x16x32_bf16(Vf[df], Pf[qf], o[df][qf], 0, 0, 0); \
            _Pragma("unroll")                                                   \
            for (int qf = 0; qf < 2; ++qf)                                      \
                lacc[qf] = __builtin_amdgcn_mfma_f32_16x16x32_bf16(ones8, Pf[qf], lacc[qf], 0, 0, 0); \
        }                                                                       \
    }

    const int ktmax = 2 * qt + 1;            // iteration count 2qt+2: even
    STAGE(0, 0);
    for (int kt = 0; kt <= ktmax; kt += 2) {
        __syncthreads();                     // staging(kt) visible
        if (kt < ktmax) STAGE(1, kt + 1);
        if (qbase + 31 >= kt * 64) COMPUTE(0, kt);

        __syncthreads();                     // staging(kt+1) visible
        if (kt + 1 < ktmax) STAGE(0, kt + 2);
        if (qbase + 31 >= (kt + 1) * 64) COMPUTE(1, kt + 1);
    }

    // ---- epilogue: l is in-lane (all C rows equal) -> no shuffles ----
    float inv[2];
#pragma unroll
    for (int qf = 0; qf < 2; ++qf) inv[qf] = 1.0f / lacc[qf][0];
#pragma unroll
    for (int df = 0; df < 4; ++df)
#pragma unroll
        for (int qf = 0; qf < 2; ++qf) {
            int q  = qbase + qf * 16 + l15;
            int dd = df * 16 + quad * 4;
            unsigned short pk[4];
#pragma unroll
            for (int r = 0; r < 4; ++r) pk[r] = f2bf(o[df][qf][r] * inv[qf]);
            *(uint2*)&Og[((size_t)b * S_ + q) * DM_ + h * DK_ + dd] = *(uint2*)pk;
        }
#undef COMPUTE
#undef STAGE
}

// ---------------------------------------------------------------------------
extern "C" void kernel_launch(void* const* d_in, const int* in_sizes, int n_in,
                              void* d_out, int out_size, void* d_ws, size_t ws_size,
                              hipStream_t stream) {
    const float* x    = (const float*)d_in[0];
    const int*   tpos = (const int*)d_in[1];
    const float* Wq   = (const float*)d_in[2];
    const float* Wk   = (const float*)d_in[3];
    const float* Wv   = (const float*)d_in[4];
    const float* Wo   = (const float*)d_in[5];
    float* out = (float*)d_out;

    const int NX = B_ * S_ * DM_;        // 8388608
    const int NW = DM_ * DM_;            // 1048576

    unsigned short* xb  = (unsigned short*)d_ws;
    unsigned short* Wqb = xb + NX;       // Wq,Wk,Wv,Wo contiguous
    unsigned short* Wob = Wqb + 3 * NW;
    unsigned short* Qb  = Wob + NW;
    unsigned short* Kb  = Qb + NX;
    unsigned short* Vtb = Kb + NX;
    unsigned short* Aw  = Vtb + NX;

    cast_all<<<NX / 1024 + 4 * (NW / 1024), 256, 0, stream>>>(x, Wq, Wk, Wv, Wo, xb);

    gemm_qkv<<<dim3(64, 24), 256, 0, stream>>>(Wqb, xb, Qb, Kb, Vtb, tpos);

    attn_mfma<<<dim3(32, 32), 256, 0, stream>>>(Qb, Kb, Vtb, Aw);

    gemm_out<<<dim3(64, 8), 256, 0, stream>>>(Wob, Aw, out);            // O-proj, fp32 out
}